// Round 1
// 395.854 us; speedup vs baseline: 1.0148x; 1.0148x over previous
//
#include <hip/hip_runtime.h>

#define IN_F 4096
#define OUT_F 4096
#define BATCH 16384

// Partial-sum decomposition: NCHUNK row-chunks, no atomics, no zero-init.
#define NCHUNK 64
#define ROWS_PER_CHUNK (OUT_F / NCHUNK)   // 64
#define PART_F4 (IN_F / 4)                // 1024 float4 columns
// ws float layout:
//   [0 .. NCHUNK*IN_F)            : partial column sums (chunk-major)
//   [CS_OFF .. CS_OFF+IN_F)       : final column sums
//   [BIAS_OFF]                    : bias sum
#define CS_OFF   (NCHUNK * IN_F)
#define BIAS_OFF (CS_OFF + IN_F)

// Kernel A: partial column sums of W (row-major [OUT_F, IN_F]).
// grid = (4, NCHUNK), block = 256. Thread owns one float4 column group;
// blockIdx.y owns a 64-row chunk. Plain stores to disjoint slots.
__global__ __launch_bounds__(256) void colsum_part(
    const float* __restrict__ W, float* __restrict__ ws) {
  int col4 = blockIdx.x * 256 + threadIdx.x;   // 0..1023
  int row0 = blockIdx.y * ROWS_PER_CHUNK;
  const float4* W4 = (const float4*)W;

  float4 acc = make_float4(0.f, 0.f, 0.f, 0.f);
  #pragma unroll 8
  for (int r = 0; r < ROWS_PER_CHUNK; ++r) {
    float4 v = W4[(size_t)(row0 + r) * PART_F4 + col4];
    acc.x += v.x; acc.y += v.y; acc.z += v.z; acc.w += v.w;
  }
  ((float4*)ws)[(size_t)blockIdx.y * PART_F4 + col4] = acc;
}

// Kernel B: reduce NCHUNK partials per column + bias sum.
// grid = 5, block = 256. Blocks 0..3: columns (coalesced strided reads,
// ~1 MiB from L2). Block 4, wave 0: bias reduction.
__global__ __launch_bounds__(256) void colsum_reduce(
    const float* __restrict__ bias, float* __restrict__ ws) {
  if (blockIdx.x < 4) {
    int col4 = blockIdx.x * 256 + threadIdx.x;  // 0..1023
    const float4* p4 = (const float4*)ws;
    float4 acc = make_float4(0.f, 0.f, 0.f, 0.f);
    #pragma unroll 8
    for (int k = 0; k < NCHUNK; ++k) {
      float4 v = p4[(size_t)k * PART_F4 + col4];
      acc.x += v.x; acc.y += v.y; acc.z += v.z; acc.w += v.w;
    }
    ((float4*)(ws + CS_OFF))[col4] = acc;
  } else if (threadIdx.x < 64) {
    float b = 0.f;
    #pragma unroll
    for (int i = 0; i < OUT_F / 64; ++i) b += bias[threadIdx.x + i * 64];
    #pragma unroll
    for (int off = 32; off > 0; off >>= 1) b += __shfl_down(b, off);
    if (threadIdx.x == 0) ws[BIAS_OFF] = b;
  }
}

// Kernel C: out[row] = dot(x[row,:], colsum) + bias_sum.
// grid = BATCH/4, block = 256 (4 waves, 1 row per wave).
// No LDS: the 16 KiB colsum vector is shared by every block and stays
// L1-resident (32 KiB L1/CU); x streams at HBM pace.
__global__ __launch_bounds__(256) void rowdot_kernel(
    const float* __restrict__ x, const float* __restrict__ ws,
    float* __restrict__ out) {
  int wave = threadIdx.x >> 6;
  int lane = threadIdx.x & 63;
  int row  = blockIdx.x * 4 + wave;

  const float4* xr  = (const float4*)(x + (size_t)row * IN_F);
  const float4* cs4 = (const float4*)(ws + CS_OFF);

  float acc = 0.f;
  #pragma unroll
  for (int it = 0; it < IN_F / 4 / 64; ++it) {  // 16 iterations
    float4 xv = xr[it * 64 + lane];
    float4 wv = cs4[it * 64 + lane];
    acc += xv.x * wv.x + xv.y * wv.y + xv.z * wv.z + xv.w * wv.w;
  }
  #pragma unroll
  for (int off = 32; off > 0; off >>= 1) acc += __shfl_down(acc, off);
  if (lane == 0) out[row] = acc + ws[BIAS_OFF];
}

extern "C" void kernel_launch(void* const* d_in, const int* in_sizes, int n_in,
                              void* d_out, int out_size, void* d_ws, size_t ws_size,
                              hipStream_t stream) {
  const float* x    = (const float*)d_in[0];
  const float* W    = (const float*)d_in[1];
  const float* bias = (const float*)d_in[2];
  float* out = (float*)d_out;
  float* ws  = (float*)d_ws;

  // No memset: every ws slot consumed is fully written first (re-poison safe).
  colsum_part<<<dim3(4, NCHUNK), 256, 0, stream>>>(W, ws);
  colsum_reduce<<<5, 256, 0, stream>>>(bias, ws);
  rowdot_kernel<<<BATCH / 4, 256, 0, stream>>>(x, ws, out);
}